// Round 1
// baseline (952.934 us; speedup 1.0000x reference)
//
#include <hip/hip_runtime.h>
#include <cmath>

#define V 8192
#define NREF 262144
#define NALT 131072
#define NREADS (NREF + NALT)
#define FR 11
#define FI 9
#define HH 256
#define MAX_ALT 10

#define TILE_R 64
#define HPAD 68   // row stride for transposed H tile: 68*4=272B, 16B-aligned rows
#define VB 8      // variants per block in kernel B

__device__ __forceinline__ float sigmoidf_(float x) {
    return __builtin_amdgcn_rcpf(1.0f + __expf(-x));
}
__device__ __forceinline__ float lrelu_(float x) {
    return x > 0.0f ? x : 0.01f * x;
}

// ---------------------------------------------------------------------------
// Kernel A: fused phi MLP (GEMM1 + GEMM2 + sigmoid) + segment sum/count.
// One block = 64 consecutive reads (tiles never straddle the ref/alt split
// since NREF % 64 == 0). Thread t: GEMM1 computes H[:,t]; GEMM2 uses a
// 16-read x 4-col register tile (c4=(t&63)*4, rb=(t>>6)*16).
// ---------------------------------------------------------------------------
__global__ __launch_bounds__(256) void phi_seg_kernel(
    const float* __restrict__ reads,
    const int* __restrict__ ref_ids, const int* __restrict__ alt_ids,
    const float* __restrict__ W0, const float* __restrict__ b0,
    const float* __restrict__ W1, const float* __restrict__ b1,
    float* __restrict__ ref_sums, float* __restrict__ alt_sums,
    int* __restrict__ ref_cnt, int* __restrict__ alt_cnt)
{
    __shared__ float sHT[HH][HPAD];          // H transposed: sHT[k][r]
    __shared__ float sReads[TILE_R][FR + 1]; // +1 pad
    __shared__ int   sSeg[TILE_R];

    const int t  = threadIdx.x;
    const int r0 = blockIdx.x * TILE_R;
    const bool is_ref = (r0 < NREF);
    const int* seg_ids = is_ref ? ref_ids : alt_ids;
    const int sbase    = is_ref ? r0 : (r0 - NREF);
    float* sums = is_ref ? ref_sums : alt_sums;
    int*   cnts = is_ref ? ref_cnt  : alt_cnt;

    for (int idx = t; idx < TILE_R * FR; idx += 256) {
        int r = idx / FR, k = idx - r * FR;
        sReads[r][k] = reads[(size_t)(r0 + r) * FR + k];
    }
    if (t < TILE_R) sSeg[t] = seg_ids[sbase + t];

    // GEMM1 weights for column t
    float w0r[FR];
#pragma unroll
    for (int k = 0; k < FR; k++) w0r[k] = W0[k * HH + t];
    const float b0v = b0[t];
    __syncthreads();

    // GEMM1: H[r][t] = lrelu(reads[r,:] . W0[:,t] + b0[t]) -> sHT[t][r]
#pragma unroll 4
    for (int r = 0; r < TILE_R; r++) {
        float a = b0v;
#pragma unroll
        for (int k = 0; k < FR; k++) a = fmaf(sReads[r][k], w0r[k], a);
        sHT[t][r] = lrelu_(a);
    }
    __syncthreads();

    // GEMM2: P[r][c] = sigmoid(H[r,:] . W1[:,c] + b1[c])
    const int c4 = (t & 63) * 4;   // 4 consecutive output cols
    const int rb = (t >> 6) * 16;  // 16 consecutive reads (wave-uniform)

    float acc[16][4];
    const float4 b1v = *(const float4*)(b1 + c4);
#pragma unroll
    for (int r = 0; r < 16; r++) {
        acc[r][0] = b1v.x; acc[r][1] = b1v.y; acc[r][2] = b1v.z; acc[r][3] = b1v.w;
    }

#pragma unroll 2
    for (int k = 0; k < HH; k++) {
        const float4 w = *(const float4*)(W1 + (size_t)k * HH + c4);
        const float4* hp = (const float4*)(&sHT[k][rb]); // 16B-aligned, wave-broadcast
        float hv[16];
        *(float4*)&hv[0]  = hp[0];
        *(float4*)&hv[4]  = hp[1];
        *(float4*)&hv[8]  = hp[2];
        *(float4*)&hv[12] = hp[3];
#pragma unroll
        for (int r = 0; r < 16; r++) {
            acc[r][0] = fmaf(hv[r], w.x, acc[r][0]);
            acc[r][1] = fmaf(hv[r], w.y, acc[r][1]);
            acc[r][2] = fmaf(hv[r], w.z, acc[r][2]);
            acc[r][3] = fmaf(hv[r], w.w, acc[r][3]);
        }
    }

    // sigmoid + run-compressed segment atomics (seg ids sorted; branch is
    // wave-uniform since rb and sSeg are uniform across the wave)
    int cur = sSeg[rb];
    float run0 = 0.f, run1 = 0.f, run2 = 0.f, run3 = 0.f;
    int runlen = 0;
#pragma unroll
    for (int r = 0; r < 16; r++) {
        int s = sSeg[rb + r];
        if (s != cur) {
            float* dst = sums + (size_t)cur * HH + c4;
            atomicAdd(dst + 0, run0);
            atomicAdd(dst + 1, run1);
            atomicAdd(dst + 2, run2);
            atomicAdd(dst + 3, run3);
            if ((t & 63) == 0) atomicAdd(&cnts[cur], runlen);
            run0 = run1 = run2 = run3 = 0.f; runlen = 0; cur = s;
        }
        run0 += sigmoidf_(acc[r][0]);
        run1 += sigmoidf_(acc[r][1]);
        run2 += sigmoidf_(acc[r][2]);
        run3 += sigmoidf_(acc[r][3]);
        runlen++;
    }
    {
        float* dst = sums + (size_t)cur * HH + c4;
        atomicAdd(dst + 0, run0);
        atomicAdd(dst + 1, run1);
        atomicAdd(dst + 2, run2);
        atomicAdd(dst + 3, run3);
        if ((t & 63) == 0) atomicAdd(&cnts[cur], runlen);
    }
}

// ---------------------------------------------------------------------------
// Kernel B: per-variant means + omega + rho MLP + 3 out-heads + select/tanh.
// One block = VB=8 variants; weight loads amortized 8x across variants.
// ---------------------------------------------------------------------------
__global__ __launch_bounds__(256) void rho_out_kernel(
    const float* __restrict__ info, const int* __restrict__ vtypes,
    const float* __restrict__ om_W0, const float* __restrict__ om_b0,
    const float* __restrict__ rho_W0, const float* __restrict__ rho_b0,
    const float* __restrict__ rho_W1, const float* __restrict__ rho_b1,
    const float* __restrict__ out_W1, const float* __restrict__ out_b1,
    const float* __restrict__ out_W2, const float* __restrict__ out_b2,
    const float* __restrict__ conf, const float* __restrict__ max_logit,
    const float* __restrict__ ref_sums, const float* __restrict__ alt_sums,
    const int* __restrict__ ref_cnt, const int* __restrict__ alt_cnt,
    float* __restrict__ out)
{
    __shared__ float sC[VB][768];    // concat [ref_mean | alt_mean | omega]
    __shared__ float sA1[VB][HH];
    __shared__ float sAgg[VB][HH];
    __shared__ float sInfo[VB][FI];
    __shared__ float sRed[4][3 * VB];
    __shared__ int   sACnt[VB];

    const int t  = threadIdx.x;
    const int v0 = blockIdx.x * VB;

    if (t < VB * FI) {
        int i = t / FI, k = t - i * FI;
        sInfo[i][k] = info[(size_t)(v0 + i) * FI + k];
    }
    if (t < VB) sACnt[t] = alt_cnt[v0 + t];
    __syncthreads();

    // Stage 1: means + omega -> sC
    float om0r[FI];
#pragma unroll
    for (int k = 0; k < FI; k++) om0r[k] = om_W0[k * HH + t];
    const float ombv = om_b0[t];

#pragma unroll
    for (int i = 0; i < VB; i++) {
        const int v = v0 + i;
        float rc = (float)ref_cnt[v];
        float ac = (float)sACnt[i];
        float rinv = __builtin_amdgcn_rcpf(fmaxf(rc, 1.0f));
        float ainv = __builtin_amdgcn_rcpf(fmaxf(ac, 1.0f));
        sC[i][t]        = ref_sums[(size_t)v * HH + t] * rinv;
        sC[i][HH + t]   = alt_sums[(size_t)v * HH + t] * ainv;
        float a = ombv;
#pragma unroll
        for (int k = 0; k < FI; k++) a = fmaf(sInfo[i][k], om0r[k], a);
        sC[i][2 * HH + t] = sigmoidf_(a);
    }
    __syncthreads();

    // Stage 2: a1 = lrelu(concat @ rho_W0 + rho_b0)
    float acc[VB];
    {
        const float b = rho_b0[t];
#pragma unroll
        for (int i = 0; i < VB; i++) acc[i] = b;
    }
    for (int k = 0; k < 3 * HH; k += 4) {
        float w0_ = rho_W0[(k + 0) * HH + t];
        float w1_ = rho_W0[(k + 1) * HH + t];
        float w2_ = rho_W0[(k + 2) * HH + t];
        float w3_ = rho_W0[(k + 3) * HH + t];
#pragma unroll
        for (int i = 0; i < VB; i++) {
            float4 cv = *(const float4*)(&sC[i][k]);
            acc[i] = fmaf(cv.x, w0_, acc[i]);
            acc[i] = fmaf(cv.y, w1_, acc[i]);
            acc[i] = fmaf(cv.z, w2_, acc[i]);
            acc[i] = fmaf(cv.w, w3_, acc[i]);
        }
    }
#pragma unroll
    for (int i = 0; i < VB; i++) sA1[i][t] = lrelu_(acc[i]);
    __syncthreads();

    // Stage 3: agg = a1 @ rho_W1 + rho_b1   (no activation)
    {
        const float b = rho_b1[t];
#pragma unroll
        for (int i = 0; i < VB; i++) acc[i] = b;
    }
    for (int k = 0; k < HH; k += 4) {
        float w0_ = rho_W1[(k + 0) * HH + t];
        float w1_ = rho_W1[(k + 1) * HH + t];
        float w2_ = rho_W1[(k + 2) * HH + t];
        float w3_ = rho_W1[(k + 3) * HH + t];
#pragma unroll
        for (int i = 0; i < VB; i++) {
            float4 av = *(const float4*)(&sA1[i][k]);
            acc[i] = fmaf(av.x, w0_, acc[i]);
            acc[i] = fmaf(av.y, w1_, acc[i]);
            acc[i] = fmaf(av.z, w2_, acc[i]);
            acc[i] = fmaf(av.w, w3_, acc[i]);
        }
    }
#pragma unroll
    for (int i = 0; i < VB; i++) sAgg[i][t] = acc[i];
    __syncthreads();

    // Stage 4: o[t3] = lrelu(agg @ out_W1[t3] + out_b1[t3]), all 3 heads
    float acc3[3][VB];
#pragma unroll
    for (int t3 = 0; t3 < 3; t3++) {
        const float b = out_b1[t3 * HH + t];
#pragma unroll
        for (int i = 0; i < VB; i++) acc3[t3][i] = b;
    }
    for (int d = 0; d < HH; d += 4) {
        float w[3][4];
#pragma unroll
        for (int t3 = 0; t3 < 3; t3++)
#pragma unroll
            for (int j = 0; j < 4; j++)
                w[t3][j] = out_W1[(size_t)t3 * HH * HH + (d + j) * HH + t];
#pragma unroll
        for (int i = 0; i < VB; i++) {
            float4 av = *(const float4*)(&sAgg[i][d]);
#pragma unroll
            for (int t3 = 0; t3 < 3; t3++) {
                acc3[t3][i] = fmaf(av.x, w[t3][0], acc3[t3][i]);
                acc3[t3][i] = fmaf(av.y, w[t3][1], acc3[t3][i]);
                acc3[t3][i] = fmaf(av.z, w[t3][2], acc3[t3][i]);
                acc3[t3][i] = fmaf(av.w, w[t3][3], acc3[t3][i]);
            }
        }
    }

    // Stage 5: contrib = lrelu(o) * out_W2, block-reduce over 256 threads
    const float w2r[3] = { out_W2[t], out_W2[HH + t], out_W2[2 * HH + t] };
    const int lane = t & 63, wid = t >> 6;
#pragma unroll
    for (int t3 = 0; t3 < 3; t3++) {
#pragma unroll
        for (int i = 0; i < VB; i++) {
            float val = lrelu_(acc3[t3][i]) * w2r[t3];
#pragma unroll
            for (int off = 32; off > 0; off >>= 1)
                val += __shfl_down(val, off);
            if (lane == 0) sRed[wid][t3 * VB + i] = val;
        }
    }
    __syncthreads();
    if (t < 3 * VB) {
        sRed[0][t] = sRed[0][t] + sRed[1][t] + sRed[2][t] + sRed[3][t];
    }
    __syncthreads();
    if (t < VB) {
        const int v = v0 + t;
        const int ty = vtypes[v];
        float logit = sRed[0][ty * VB + t] + out_b2[ty];
        const int tr = min(sACnt[t], MAX_ALT);
        logit *= conf[tr];
        const float ml = max_logit[0];
        out[v] = ml * tanhf(logit / ml);
    }
}

// ---------------------------------------------------------------------------
extern "C" void kernel_launch(void* const* d_in, const int* in_sizes, int n_in,
                              void* d_out, int out_size, void* d_ws, size_t ws_size,
                              hipStream_t stream) {
    const float* reads    = (const float*)d_in[0];
    const float* info     = (const float*)d_in[1];
    const int*   ref_ids  = (const int*)d_in[2];
    const int*   alt_ids  = (const int*)d_in[3];
    const int*   vtypes   = (const int*)d_in[4];
    const float* phi_W0   = (const float*)d_in[5];
    const float* phi_b0   = (const float*)d_in[6];
    const float* phi_W1   = (const float*)d_in[7];
    const float* phi_b1   = (const float*)d_in[8];
    const float* om_W0    = (const float*)d_in[9];
    const float* om_b0    = (const float*)d_in[10];
    const float* rho_W0   = (const float*)d_in[11];
    const float* rho_b0   = (const float*)d_in[12];
    const float* rho_W1   = (const float*)d_in[13];
    const float* rho_b1   = (const float*)d_in[14];
    const float* out_W1   = (const float*)d_in[15];
    const float* out_b1   = (const float*)d_in[16];
    const float* out_W2   = (const float*)d_in[17];
    const float* out_b2   = (const float*)d_in[18];
    const float* conf     = (const float*)d_in[19];
    const float* max_lg   = (const float*)d_in[20];
    float* out = (float*)d_out;

    // workspace layout: ref_sums | alt_sums | ref_cnt | alt_cnt
    float* ref_sums = (float*)d_ws;
    float* alt_sums = ref_sums + (size_t)V * HH;
    int*   ref_cnt  = (int*)(alt_sums + (size_t)V * HH);
    int*   alt_cnt  = ref_cnt + V;
    const size_t zero_bytes = (size_t)2 * V * HH * sizeof(float) + (size_t)2 * V * sizeof(int);
    hipMemsetAsync(d_ws, 0, zero_bytes, stream);

    phi_seg_kernel<<<NREADS / TILE_R, 256, 0, stream>>>(
        reads, ref_ids, alt_ids, phi_W0, phi_b0, phi_W1, phi_b1,
        ref_sums, alt_sums, ref_cnt, alt_cnt);

    rho_out_kernel<<<V / VB, 256, 0, stream>>>(
        info, vtypes, om_W0, om_b0, rho_W0, rho_b0, rho_W1, rho_b1,
        out_W1, out_b1, out_W2, out_b2, conf, max_lg,
        ref_sums, alt_sums, ref_cnt, alt_cnt, out);
}

// Round 2
// 531.326 us; speedup vs baseline: 1.7935x; 1.7935x over previous
//
#include <hip/hip_runtime.h>
#include <cmath>

#define V 8192
#define NREF 262144
#define NALT 131072
#define NREADS (NREF + NALT)
#define FR 11
#define FI 9
#define HH 256
#define MAX_ALT 10

#define TILE_R 64
#define VB 8      // variants per block in kernel B

// LDS pitches for kernel A
#define HPITCH 264   // bf16 H tile pitch: 264*2=528B, 16B-aligned, banks spread
#define PPITCH 260   // f32 P tile pitch

typedef short bf16x8 __attribute__((ext_vector_type(8)));
typedef float f32x4  __attribute__((ext_vector_type(4)));

__device__ __forceinline__ float sigmoidf_(float x) {
    return __builtin_amdgcn_rcpf(1.0f + __expf(-x));
}
__device__ __forceinline__ float lrelu_(float x) {
    return x > 0.0f ? x : 0.01f * x;
}
// fp32 -> bf16 bits, round-to-nearest-even
__device__ __forceinline__ unsigned short f2bf_(float f) {
    unsigned int u = __float_as_uint(f);
    u += 0x7FFFu + ((u >> 16) & 1u);
    return (unsigned short)(u >> 16);
}

// ---------------------------------------------------------------------------
// Precompute: W1T[n][k] = bf16(phi_W1[k][n]), 256x256
// ---------------------------------------------------------------------------
__global__ void w1t_kernel(const float* __restrict__ W1, unsigned short* __restrict__ w1t) {
    const int n = blockIdx.x, k = threadIdx.x;
    w1t[n * HH + k] = f2bf_(W1[k * HH + n]);
}

// ---------------------------------------------------------------------------
// Kernel A: fused phi MLP. GEMM1 (fp32 VALU) -> bf16 H tile in LDS ->
// GEMM2 via mfma_f32_16x16x32_bf16 -> sigmoid -> P tile in LDS (union) ->
// per-column run-compressed segment atomics.
// Block = 64 consecutive reads (never straddles ref/alt: NREF%64==0).
// 4 waves; wave w owns output cols [w*64, w*64+64).
// ---------------------------------------------------------------------------
__global__ __launch_bounds__(256) void phi_seg_kernel(
    const float* __restrict__ reads,
    const int* __restrict__ ref_ids, const int* __restrict__ alt_ids,
    const float* __restrict__ W0, const float* __restrict__ b0,
    const unsigned short* __restrict__ w1t, const float* __restrict__ b1,
    float* __restrict__ ref_sums, float* __restrict__ alt_sums,
    int* __restrict__ ref_cnt, int* __restrict__ alt_cnt)
{
    // union: bf16 H [64][HPITCH] (33792 B)  |  f32 P [64][PPITCH] (66560 B)
    __shared__ __align__(16) unsigned char uSmem[TILE_R * PPITCH * 4];
    __shared__ float sReads[TILE_R][12];
    __shared__ int   sSeg[TILE_R];

    unsigned short* sH = (unsigned short*)uSmem;
    float*          sP = (float*)uSmem;

    const int t  = threadIdx.x;
    const int r0 = blockIdx.x * TILE_R;
    const bool is_ref = (r0 < NREF);
    const int* seg_ids = is_ref ? ref_ids : alt_ids;
    const int sbase    = is_ref ? r0 : (r0 - NREF);
    float* sums = is_ref ? ref_sums : alt_sums;
    int*   cnts = is_ref ? ref_cnt  : alt_cnt;

    for (int idx = t; idx < TILE_R * FR; idx += 256) {
        int r = idx / FR, k = idx - r * FR;
        sReads[r][k] = reads[(size_t)(r0 + r) * FR + k];
    }
    if (t < TILE_R) sSeg[t] = seg_ids[sbase + t];

    // GEMM1 weights for column t
    float w0r[FR];
#pragma unroll
    for (int k = 0; k < FR; k++) w0r[k] = W0[k * HH + t];
    const float b0v = b0[t];
    __syncthreads();

    // GEMM1: H[r][t] = lrelu(reads[r,:].W0[:,t] + b0[t]) -> bf16 sH[r][t]
#pragma unroll 4
    for (int r = 0; r < TILE_R; r++) {
        float a = b0v;
#pragma unroll
        for (int k = 0; k < FR; k++) a = fmaf(sReads[r][k], w0r[k], a);
        sH[r * HPITCH + t] = f2bf_(lrelu_(a));
    }
    __syncthreads();

    // GEMM2 via MFMA: D(64x64 per wave) = H(64x256) . W1(256x64-slice)
    const int wv   = t >> 6;
    const int lane = t & 63;
    const int lrow = lane & 15;
    const int quad = lane >> 4;
    const unsigned short* wslice = w1t + (size_t)(wv * 64) * HH;

    f32x4 acc[4][4];
#pragma unroll
    for (int mt = 0; mt < 4; mt++)
#pragma unroll
        for (int nt = 0; nt < 4; nt++)
            acc[mt][nt] = (f32x4){0.f, 0.f, 0.f, 0.f};

#pragma unroll
    for (int kk = 0; kk < 8; kk++) {
        bf16x8 am[4], bn[4];
#pragma unroll
        for (int mt = 0; mt < 4; mt++)
            am[mt] = *(const bf16x8*)(sH + (mt * 16 + lrow) * HPITCH + kk * 32 + quad * 8);
#pragma unroll
        for (int nt = 0; nt < 4; nt++)
            bn[nt] = *(const bf16x8*)(wslice + (nt * 16 + lrow) * HH + kk * 32 + quad * 8);
#pragma unroll
        for (int mt = 0; mt < 4; mt++)
#pragma unroll
            for (int nt = 0; nt < 4; nt++)
                acc[mt][nt] = __builtin_amdgcn_mfma_f32_16x16x32_bf16(
                    am[mt], bn[nt], acc[mt][nt], 0, 0, 0);
    }
    __syncthreads();   // everyone done reading sH; safe to overwrite with sP

    // bias + sigmoid -> sP. C layout: col=lane&15, row=quad*4+reg (per tile)
#pragma unroll
    for (int nt = 0; nt < 4; nt++) {
        const float bb = b1[wv * 64 + nt * 16 + lrow];
        const int col = wv * 64 + nt * 16 + lrow;
#pragma unroll
        for (int mt = 0; mt < 4; mt++) {
            const int rbase = mt * 16 + quad * 4;
#pragma unroll
            for (int r = 0; r < 4; r++)
                sP[(rbase + r) * PPITCH + col] = sigmoidf_(acc[mt][nt][r] + bb);
        }
    }
    __syncthreads();

    // per-column run-compressed segment reduction (seg ids sorted; the
    // run-boundary branch is block-uniform)
    int cur = sSeg[0];
    float run = 0.f;
    int runlen = 0;
    for (int r = 0; r < TILE_R; r++) {
        const int s = sSeg[r];
        if (s != cur) {
            atomicAdd(&sums[(size_t)cur * HH + t], run);
            if (t == 0) atomicAdd(&cnts[cur], runlen);
            run = 0.f; runlen = 0; cur = s;
        }
        run += sP[r * PPITCH + t];
        runlen++;
    }
    atomicAdd(&sums[(size_t)cur * HH + t], run);
    if (t == 0) atomicAdd(&cnts[cur], runlen);
}

// ---------------------------------------------------------------------------
// Kernel B: per-variant means + omega + rho MLP + 3 out-heads + select/tanh.
// (unchanged from round 1 — to be attacked next round with its own rocprof)
// ---------------------------------------------------------------------------
__global__ __launch_bounds__(256) void rho_out_kernel(
    const float* __restrict__ info, const int* __restrict__ vtypes,
    const float* __restrict__ om_W0, const float* __restrict__ om_b0,
    const float* __restrict__ rho_W0, const float* __restrict__ rho_b0,
    const float* __restrict__ rho_W1, const float* __restrict__ rho_b1,
    const float* __restrict__ out_W1, const float* __restrict__ out_b1,
    const float* __restrict__ out_W2, const float* __restrict__ out_b2,
    const float* __restrict__ conf, const float* __restrict__ max_logit,
    const float* __restrict__ ref_sums, const float* __restrict__ alt_sums,
    const int* __restrict__ ref_cnt, const int* __restrict__ alt_cnt,
    float* __restrict__ out)
{
    __shared__ float sC[VB][768];
    __shared__ float sA1[VB][HH];
    __shared__ float sAgg[VB][HH];
    __shared__ float sInfo[VB][FI];
    __shared__ float sRed[4][3 * VB];
    __shared__ int   sACnt[VB];

    const int t  = threadIdx.x;
    const int v0 = blockIdx.x * VB;

    if (t < VB * FI) {
        int i = t / FI, k = t - i * FI;
        sInfo[i][k] = info[(size_t)(v0 + i) * FI + k];
    }
    if (t < VB) sACnt[t] = alt_cnt[v0 + t];
    __syncthreads();

    float om0r[FI];
#pragma unroll
    for (int k = 0; k < FI; k++) om0r[k] = om_W0[k * HH + t];
    const float ombv = om_b0[t];

#pragma unroll
    for (int i = 0; i < VB; i++) {
        const int v = v0 + i;
        float rc = (float)ref_cnt[v];
        float ac = (float)sACnt[i];
        float rinv = __builtin_amdgcn_rcpf(fmaxf(rc, 1.0f));
        float ainv = __builtin_amdgcn_rcpf(fmaxf(ac, 1.0f));
        sC[i][t]        = ref_sums[(size_t)v * HH + t] * rinv;
        sC[i][HH + t]   = alt_sums[(size_t)v * HH + t] * ainv;
        float a = ombv;
#pragma unroll
        for (int k = 0; k < FI; k++) a = fmaf(sInfo[i][k], om0r[k], a);
        sC[i][2 * HH + t] = sigmoidf_(a);
    }
    __syncthreads();

    float acc[VB];
    {
        const float b = rho_b0[t];
#pragma unroll
        for (int i = 0; i < VB; i++) acc[i] = b;
    }
    for (int k = 0; k < 3 * HH; k += 4) {
        float w0_ = rho_W0[(k + 0) * HH + t];
        float w1_ = rho_W0[(k + 1) * HH + t];
        float w2_ = rho_W0[(k + 2) * HH + t];
        float w3_ = rho_W0[(k + 3) * HH + t];
#pragma unroll
        for (int i = 0; i < VB; i++) {
            float4 cv = *(const float4*)(&sC[i][k]);
            acc[i] = fmaf(cv.x, w0_, acc[i]);
            acc[i] = fmaf(cv.y, w1_, acc[i]);
            acc[i] = fmaf(cv.z, w2_, acc[i]);
            acc[i] = fmaf(cv.w, w3_, acc[i]);
        }
    }
#pragma unroll
    for (int i = 0; i < VB; i++) sA1[i][t] = lrelu_(acc[i]);
    __syncthreads();

    {
        const float b = rho_b1[t];
#pragma unroll
        for (int i = 0; i < VB; i++) acc[i] = b;
    }
    for (int k = 0; k < HH; k += 4) {
        float w0_ = rho_W1[(k + 0) * HH + t];
        float w1_ = rho_W1[(k + 1) * HH + t];
        float w2_ = rho_W1[(k + 2) * HH + t];
        float w3_ = rho_W1[(k + 3) * HH + t];
#pragma unroll
        for (int i = 0; i < VB; i++) {
            float4 av = *(const float4*)(&sA1[i][k]);
            acc[i] = fmaf(av.x, w0_, acc[i]);
            acc[i] = fmaf(av.y, w1_, acc[i]);
            acc[i] = fmaf(av.z, w2_, acc[i]);
            acc[i] = fmaf(av.w, w3_, acc[i]);
        }
    }
#pragma unroll
    for (int i = 0; i < VB; i++) sAgg[i][t] = acc[i];
    __syncthreads();

    float acc3[3][VB];
#pragma unroll
    for (int t3 = 0; t3 < 3; t3++) {
        const float b = out_b1[t3 * HH + t];
#pragma unroll
        for (int i = 0; i < VB; i++) acc3[t3][i] = b;
    }
    for (int d = 0; d < HH; d += 4) {
        float w[3][4];
#pragma unroll
        for (int t3 = 0; t3 < 3; t3++)
#pragma unroll
            for (int j = 0; j < 4; j++)
                w[t3][j] = out_W1[(size_t)t3 * HH * HH + (d + j) * HH + t];
#pragma unroll
        for (int i = 0; i < VB; i++) {
            float4 av = *(const float4*)(&sAgg[i][d]);
#pragma unroll
            for (int t3 = 0; t3 < 3; t3++) {
                acc3[t3][i] = fmaf(av.x, w[t3][0], acc3[t3][i]);
                acc3[t3][i] = fmaf(av.y, w[t3][1], acc3[t3][i]);
                acc3[t3][i] = fmaf(av.z, w[t3][2], acc3[t3][i]);
                acc3[t3][i] = fmaf(av.w, w[t3][3], acc3[t3][i]);
            }
        }
    }

    const float w2r[3] = { out_W2[t], out_W2[HH + t], out_W2[2 * HH + t] };
    const int lane = t & 63, wid = t >> 6;
#pragma unroll
    for (int t3 = 0; t3 < 3; t3++) {
#pragma unroll
        for (int i = 0; i < VB; i++) {
            float val = lrelu_(acc3[t3][i]) * w2r[t3];
#pragma unroll
            for (int off = 32; off > 0; off >>= 1)
                val += __shfl_down(val, off);
            if (lane == 0) sRed[wid][t3 * VB + i] = val;
        }
    }
    __syncthreads();
    if (t < 3 * VB) {
        sRed[0][t] = sRed[0][t] + sRed[1][t] + sRed[2][t] + sRed[3][t];
    }
    __syncthreads();
    if (t < VB) {
        const int v = v0 + t;
        const int ty = vtypes[v];
        float logit = sRed[0][ty * VB + t] + out_b2[ty];
        const int tr = min(sACnt[t], MAX_ALT);
        logit *= conf[tr];
        const float ml = max_logit[0];
        out[v] = ml * tanhf(logit / ml);
    }
}

// ---------------------------------------------------------------------------
extern "C" void kernel_launch(void* const* d_in, const int* in_sizes, int n_in,
                              void* d_out, int out_size, void* d_ws, size_t ws_size,
                              hipStream_t stream) {
    const float* reads    = (const float*)d_in[0];
    const float* info     = (const float*)d_in[1];
    const int*   ref_ids  = (const int*)d_in[2];
    const int*   alt_ids  = (const int*)d_in[3];
    const int*   vtypes   = (const int*)d_in[4];
    const float* phi_W0   = (const float*)d_in[5];
    const float* phi_b0   = (const float*)d_in[6];
    const float* phi_W1   = (const float*)d_in[7];
    const float* phi_b1   = (const float*)d_in[8];
    const float* om_W0    = (const float*)d_in[9];
    const float* om_b0    = (const float*)d_in[10];
    const float* rho_W0   = (const float*)d_in[11];
    const float* rho_b0   = (const float*)d_in[12];
    const float* rho_W1   = (const float*)d_in[13];
    const float* rho_b1   = (const float*)d_in[14];
    const float* out_W1   = (const float*)d_in[15];
    const float* out_b1   = (const float*)d_in[16];
    const float* out_W2   = (const float*)d_in[17];
    const float* out_b2   = (const float*)d_in[18];
    const float* conf     = (const float*)d_in[19];
    const float* max_lg   = (const float*)d_in[20];
    float* out = (float*)d_out;

    // workspace: ref_sums | alt_sums | ref_cnt | alt_cnt | W1T(bf16)
    float* ref_sums = (float*)d_ws;
    float* alt_sums = ref_sums + (size_t)V * HH;
    int*   ref_cnt  = (int*)(alt_sums + (size_t)V * HH);
    int*   alt_cnt  = ref_cnt + V;
    unsigned short* w1t = (unsigned short*)(alt_cnt + V);

    const size_t zero_bytes = (size_t)2 * V * HH * sizeof(float) + (size_t)2 * V * sizeof(int);
    hipMemsetAsync(d_ws, 0, zero_bytes, stream);

    w1t_kernel<<<HH, HH, 0, stream>>>(phi_W1, w1t);

    phi_seg_kernel<<<NREADS / TILE_R, 256, 0, stream>>>(
        reads, ref_ids, alt_ids, phi_W0, phi_b0, w1t, phi_b1,
        ref_sums, alt_sums, ref_cnt, alt_cnt);

    rho_out_kernel<<<V / VB, 256, 0, stream>>>(
        info, vtypes, om_W0, om_b0, rho_W0, rho_b0, rho_W1, rho_b1,
        out_W1, out_b1, out_W2, out_b2, conf, max_lg,
        ref_sums, alt_sums, ref_cnt, alt_cnt, out);
}

// Round 3
// 342.621 us; speedup vs baseline: 2.7813x; 1.5508x over previous
//
#include <hip/hip_runtime.h>
#include <cmath>

#define V 8192
#define NREF 262144
#define NALT 131072
#define NREADS (NREF + NALT)
#define FR 11
#define FI 9
#define HH 256
#define MAX_ALT 10

#define TILE_R 64
#define HPITCH 264   // bf16 H tile pitch (shorts): 528B rows, 16B-aligned
#define PTPITCH 72   // bf16 P^T pitch (shorts): 144B rows, 16B-aligned

#define TILE_V 32
#define CPITCH 776   // bf16 concat pitch (shorts): 1552B, 16B-aligned
#define APITCH 264   // bf16 A1/agg pitch

typedef short bf16x8 __attribute__((ext_vector_type(8)));
typedef float f32x4  __attribute__((ext_vector_type(4)));

__device__ __forceinline__ float sigmoidf_(float x) {
    return __builtin_amdgcn_rcpf(1.0f + __expf(-x));
}
__device__ __forceinline__ float lrelu_(float x) {
    return x > 0.0f ? x : 0.01f * x;
}
__device__ __forceinline__ unsigned short f2bf_(float f) {
    unsigned int u = __float_as_uint(f);
    u += 0x7FFFu + ((u >> 16) & 1u);
    return (unsigned short)(u >> 16);
}
__device__ __forceinline__ float bf2f_(unsigned short b) {
    return __uint_as_float(((unsigned int)b) << 16);
}

// ---------------------------------------------------------------------------
// Tiled transpose + f32->bf16: dst[c][r] = bf16(src[r][c]); src is R x C.
// grid = (C/32, R/32, batch), block = 256.
// ---------------------------------------------------------------------------
__global__ void tr_bf16_kernel(const float* __restrict__ src,
                               unsigned short* __restrict__ dst,
                               int R, int C, int sBatch, int dBatch) {
    __shared__ unsigned short sT[32][33];
    const int t = threadIdx.x, tx = t & 31, ty = t >> 5;
    src += (size_t)blockIdx.z * sBatch;
    dst += (size_t)blockIdx.z * dBatch;
    const int r0 = blockIdx.y * 32, c0 = blockIdx.x * 32;
#pragma unroll
    for (int k = 0; k < 4; k++)
        sT[ty + k * 8][tx] = f2bf_(src[(size_t)(r0 + ty + k * 8) * C + c0 + tx]);
    __syncthreads();
#pragma unroll
    for (int k = 0; k < 4; k++)
        dst[(size_t)(c0 + ty + k * 8) * R + r0 + tx] = sT[tx][ty + k * 8];
}

// ---------------------------------------------------------------------------
// Kernel A: fused phi MLP + segment sum/count.
// GEMM1: thread owns 4 cols x 16 rows, weights in 44 regs (1 LDS staging).
// GEMM2: mfma_f32_16x16x32_bf16, 64x64 per wave.
// Epilogue: P^T (bf16) in LDS; thread t owns column t, run-compressed atomics.
// ---------------------------------------------------------------------------
__global__ __launch_bounds__(256) void phi_seg_kernel(
    const float* __restrict__ reads,
    const int* __restrict__ ref_ids, const int* __restrict__ alt_ids,
    const float* __restrict__ W0, const float* __restrict__ b0,
    const unsigned short* __restrict__ w1t, const float* __restrict__ b1,
    float* __restrict__ ref_sums, float* __restrict__ alt_sums,
    int* __restrict__ ref_cnt, int* __restrict__ alt_cnt)
{
    // union: bf16 H [64][HPITCH] (33792B) | bf16 P^T [256][PTPITCH] (36864B)
    __shared__ __align__(16) unsigned char uSmem[256 * PTPITCH * 2];
    __shared__ __align__(16) float sW0[FR][HH];       // 11264B
    __shared__ __align__(16) float sReads[TILE_R][12];
    __shared__ int sSeg[TILE_R];

    unsigned short* sH  = (unsigned short*)uSmem;
    unsigned short* sPT = (unsigned short*)uSmem;

    const int t  = threadIdx.x;
    const int r0 = blockIdx.x * TILE_R;
    const bool is_ref = (r0 < NREF);
    const int* seg_ids = is_ref ? ref_ids : alt_ids;
    const int sbase    = is_ref ? r0 : (r0 - NREF);
    float* sums = is_ref ? ref_sums : alt_sums;
    int*   cnts = is_ref ? ref_cnt  : alt_cnt;

    for (int idx = t; idx < FR * HH; idx += 256) ((float*)sW0)[idx] = W0[idx];
    for (int idx = t; idx < TILE_R * FR; idx += 256) {
        int r = idx / FR, k = idx - r * FR;
        sReads[r][k] = reads[(size_t)(r0 + r) * FR + k];
    }
    if (t < TILE_R) sSeg[t] = seg_ids[sbase + t];
    __syncthreads();

    // ---- GEMM1: 4 cols (c4) x 16 rows (rb) per thread ----
    const int c4 = (t & 63) * 4;
    const int rb = (t >> 6) * 16;
    float4 wr[FR];
#pragma unroll
    for (int k = 0; k < FR; k++) wr[k] = *(const float4*)&sW0[k][c4];
    const float4 bias0 = *(const float4*)(b0 + c4);

#pragma unroll
    for (int rr = 0; rr < 16; rr++) {
        const int r = rb + rr;
        float4 f0 = *(const float4*)&sReads[r][0];
        float4 f1 = *(const float4*)&sReads[r][4];
        float4 f2 = *(const float4*)&sReads[r][8];
        float fr_[FR] = {f0.x, f0.y, f0.z, f0.w, f1.x, f1.y, f1.z, f1.w,
                         f2.x, f2.y, f2.z};
        float4 a = bias0;
#pragma unroll
        for (int k = 0; k < FR; k++) {
            a.x = fmaf(fr_[k], wr[k].x, a.x);
            a.y = fmaf(fr_[k], wr[k].y, a.y);
            a.z = fmaf(fr_[k], wr[k].z, a.z);
            a.w = fmaf(fr_[k], wr[k].w, a.w);
        }
        unsigned int p01 = (unsigned int)f2bf_(lrelu_(a.x)) |
                           ((unsigned int)f2bf_(lrelu_(a.y)) << 16);
        unsigned int p23 = (unsigned int)f2bf_(lrelu_(a.z)) |
                           ((unsigned int)f2bf_(lrelu_(a.w)) << 16);
        uint2 pk = {p01, p23};
        *(uint2*)&sH[r * HPITCH + c4] = pk;
    }
    __syncthreads();

    // ---- GEMM2 via MFMA ----
    const int wv   = t >> 6;
    const int lane = t & 63;
    const int lrow = lane & 15;
    const int quad = lane >> 4;

    f32x4 acc[4][4];
#pragma unroll
    for (int mt = 0; mt < 4; mt++)
#pragma unroll
        for (int nt = 0; nt < 4; nt++)
            acc[mt][nt] = (f32x4){0.f, 0.f, 0.f, 0.f};

#pragma unroll
    for (int kk = 0; kk < 8; kk++) {
        bf16x8 am[4], bn[4];
#pragma unroll
        for (int mt = 0; mt < 4; mt++)
            am[mt] = *(const bf16x8*)(sH + (mt * 16 + lrow) * HPITCH + kk * 32 + quad * 8);
#pragma unroll
        for (int nt = 0; nt < 4; nt++)
            bn[nt] = *(const bf16x8*)(w1t + (size_t)(wv * 64 + nt * 16 + lrow) * HH + kk * 32 + quad * 8);
#pragma unroll
        for (int mt = 0; mt < 4; mt++)
#pragma unroll
            for (int nt = 0; nt < 4; nt++)
                acc[mt][nt] = __builtin_amdgcn_mfma_f32_16x16x32_bf16(
                    am[mt], bn[nt], acc[mt][nt], 0, 0, 0);
    }
    __syncthreads();   // done reading sH

    // ---- sigmoid -> P^T (bf16) ----
#pragma unroll
    for (int nt = 0; nt < 4; nt++) {
        const int col = wv * 64 + nt * 16 + lrow;
        const float bb = b1[col];
#pragma unroll
        for (int mt = 0; mt < 4; mt++) {
            unsigned int p01 =
                (unsigned int)f2bf_(sigmoidf_(acc[mt][nt][0] + bb)) |
                ((unsigned int)f2bf_(sigmoidf_(acc[mt][nt][1] + bb)) << 16);
            unsigned int p23 =
                (unsigned int)f2bf_(sigmoidf_(acc[mt][nt][2] + bb)) |
                ((unsigned int)f2bf_(sigmoidf_(acc[mt][nt][3] + bb)) << 16);
            uint2 pk = {p01, p23};
            *(uint2*)&sPT[col * PTPITCH + mt * 16 + quad * 4] = pk;
        }
    }
    __syncthreads();

    // ---- per-column run-compressed segment atomics (regs only) ----
    bf16x8 p8[8];
#pragma unroll
    for (int j = 0; j < 8; j++)
        p8[j] = *(const bf16x8*)&sPT[t * PTPITCH + j * 8];

    int cur = sSeg[0];
    float run = 0.f;
    int runlen = 0;
#pragma unroll
    for (int r = 0; r < TILE_R; r++) {
        const int s = sSeg[r];
        if (s != cur) {
            atomicAdd(&sums[(size_t)cur * HH + t], run);
            if (t == 0) atomicAdd(&cnts[cur], runlen);
            run = 0.f; runlen = 0; cur = s;
        }
        run += bf2f_((unsigned short)p8[r >> 3][r & 7]);
        runlen++;
    }
    atomicAdd(&sums[(size_t)cur * HH + t], run);
    if (t == 0) atomicAdd(&cnts[cur], runlen);
}

// ---------------------------------------------------------------------------
// Kernel B: fused MFMA chain. Block = 32 variants, 4 waves (wave = 64 cols).
// concat(bf16, LDS) -> rho0(K=768) -> rho1(K=256) -> 3 heads (K=256, A hoisted)
// -> lrelu*W2 row-reduce -> select type, conf, tanh.
// ---------------------------------------------------------------------------
__global__ __launch_bounds__(256) void rho_mfma_kernel(
    const float* __restrict__ info, const int* __restrict__ vtypes,
    const float* __restrict__ om_W0, const float* __restrict__ om_b0,
    const unsigned short* __restrict__ w0t, const float* __restrict__ rho_b0,
    const unsigned short* __restrict__ w1rt, const float* __restrict__ rho_b1,
    const unsigned short* __restrict__ whT, const float* __restrict__ out_b1,
    const float* __restrict__ out_W2, const float* __restrict__ out_b2,
    const float* __restrict__ conf, const float* __restrict__ max_logit,
    const float* __restrict__ ref_sums, const float* __restrict__ alt_sums,
    const int* __restrict__ ref_cnt, const int* __restrict__ alt_cnt,
    float* __restrict__ out)
{
    __shared__ __align__(16) unsigned short sC[TILE_V * CPITCH];  // 49664B
    __shared__ __align__(16) float sInfo[TILE_V][12];
    __shared__ float sRinvR[TILE_V], sRinvA[TILE_V];
    __shared__ float sPart[4][3][TILE_V];

    unsigned short* sA1  = sC;                     // [32][APITCH] after sC dead
    unsigned short* sAgg = sC + TILE_V * APITCH;   // disjoint region

    const int t  = threadIdx.x;
    const int v0 = blockIdx.x * TILE_V;

    for (int idx = t; idx < TILE_V * FI; idx += 256) {
        int i = idx / FI, k = idx - i * FI;
        sInfo[i][k] = info[(size_t)(v0 + i) * FI + k];
    }
    if (t < TILE_V) {
        sRinvR[t] = __builtin_amdgcn_rcpf(fmaxf((float)ref_cnt[v0 + t], 1.0f));
        sRinvA[t] = __builtin_amdgcn_rcpf(fmaxf((float)alt_cnt[v0 + t], 1.0f));
    }
    float om0r[FI];
#pragma unroll
    for (int k = 0; k < FI; k++) om0r[k] = om_W0[k * HH + t];
    const float omb = om_b0[t];
    __syncthreads();

    // ---- build concat (bf16) ----
    for (int i = 0; i < TILE_V; i++) {
        sC[i * CPITCH + t]          = f2bf_(ref_sums[(size_t)(v0 + i) * HH + t] * sRinvR[i]);
        sC[i * CPITCH + HH + t]     = f2bf_(alt_sums[(size_t)(v0 + i) * HH + t] * sRinvA[i]);
        float a = omb;
#pragma unroll
        for (int k = 0; k < FI; k++) a = fmaf(sInfo[i][k], om0r[k], a);
        sC[i * CPITCH + 2 * HH + t] = f2bf_(sigmoidf_(a));
    }
    __syncthreads();

    const int wv   = t >> 6;
    const int lane = t & 63;
    const int lrow = lane & 15;
    const int quad = lane >> 4;

    // ---- phase 1: A1 = lrelu(C @ rho_W0 + b0), K=768 ----
    f32x4 acc[2][4];
#pragma unroll
    for (int mt = 0; mt < 2; mt++)
#pragma unroll
        for (int nt = 0; nt < 4; nt++) acc[mt][nt] = (f32x4){0.f, 0.f, 0.f, 0.f};

    for (int kk = 0; kk < 24; kk++) {
        bf16x8 am[2], bn[4];
#pragma unroll
        for (int mt = 0; mt < 2; mt++)
            am[mt] = *(const bf16x8*)&sC[(mt * 16 + lrow) * CPITCH + kk * 32 + quad * 8];
#pragma unroll
        for (int nt = 0; nt < 4; nt++)
            bn[nt] = *(const bf16x8*)&w0t[(size_t)(wv * 64 + nt * 16 + lrow) * 768 + kk * 32 + quad * 8];
#pragma unroll
        for (int mt = 0; mt < 2; mt++)
#pragma unroll
            for (int nt = 0; nt < 4; nt++)
                acc[mt][nt] = __builtin_amdgcn_mfma_f32_16x16x32_bf16(
                    am[mt], bn[nt], acc[mt][nt], 0, 0, 0);
    }
    __syncthreads();   // all waves done reading sC

#pragma unroll
    for (int nt = 0; nt < 4; nt++) {
        const int col = wv * 64 + nt * 16 + lrow;
        const float bb = rho_b0[col];
#pragma unroll
        for (int mt = 0; mt < 2; mt++)
#pragma unroll
            for (int r = 0; r < 4; r++)
                sA1[(mt * 16 + quad * 4 + r) * APITCH + col] = f2bf_(lrelu_(acc[mt][nt][r] + bb));
    }
    __syncthreads();

    // ---- phase 2: agg = A1 @ rho_W1 + b1 (linear), K=256 ----
#pragma unroll
    for (int mt = 0; mt < 2; mt++)
#pragma unroll
        for (int nt = 0; nt < 4; nt++) acc[mt][nt] = (f32x4){0.f, 0.f, 0.f, 0.f};

#pragma unroll
    for (int kk = 0; kk < 8; kk++) {
        bf16x8 am[2], bn[4];
#pragma unroll
        for (int mt = 0; mt < 2; mt++)
            am[mt] = *(const bf16x8*)&sA1[(mt * 16 + lrow) * APITCH + kk * 32 + quad * 8];
#pragma unroll
        for (int nt = 0; nt < 4; nt++)
            bn[nt] = *(const bf16x8*)&w1rt[(size_t)(wv * 64 + nt * 16 + lrow) * HH + kk * 32 + quad * 8];
#pragma unroll
        for (int mt = 0; mt < 2; mt++)
#pragma unroll
            for (int nt = 0; nt < 4; nt++)
                acc[mt][nt] = __builtin_amdgcn_mfma_f32_16x16x32_bf16(
                    am[mt], bn[nt], acc[mt][nt], 0, 0, 0);
    }
#pragma unroll
    for (int nt = 0; nt < 4; nt++) {
        const int col = wv * 64 + nt * 16 + lrow;
        const float bb = rho_b1[col];
#pragma unroll
        for (int mt = 0; mt < 2; mt++)
#pragma unroll
            for (int r = 0; r < 4; r++)
                sAgg[(mt * 16 + quad * 4 + r) * APITCH + col] = f2bf_(acc[mt][nt][r] + bb);
    }
    __syncthreads();

    // ---- phase 3: 3 heads; A-fragments hoisted and reused ----
    bf16x8 aF[8][2];
#pragma unroll
    for (int kk = 0; kk < 8; kk++)
#pragma unroll
        for (int mt = 0; mt < 2; mt++)
            aF[kk][mt] = *(const bf16x8*)&sAgg[(mt * 16 + lrow) * APITCH + kk * 32 + quad * 8];

    for (int h = 0; h < 3; h++) {
        f32x4 a3[2][4];
#pragma unroll
        for (int mt = 0; mt < 2; mt++)
#pragma unroll
            for (int nt = 0; nt < 4; nt++) a3[mt][nt] = (f32x4){0.f, 0.f, 0.f, 0.f};

#pragma unroll
        for (int kk = 0; kk < 8; kk++) {
            bf16x8 bn[4];
#pragma unroll
            for (int nt = 0; nt < 4; nt++)
                bn[nt] = *(const bf16x8*)&whT[((size_t)h * HH + wv * 64 + nt * 16 + lrow) * HH + kk * 32 + quad * 8];
#pragma unroll
            for (int mt = 0; mt < 2; mt++)
#pragma unroll
                for (int nt = 0; nt < 4; nt++)
                    a3[mt][nt] = __builtin_amdgcn_mfma_f32_16x16x32_bf16(
                        aF[kk][mt], bn[nt], a3[mt][nt], 0, 0, 0);
        }

        float rs[2][4] = {{0.f, 0.f, 0.f, 0.f}, {0.f, 0.f, 0.f, 0.f}};
#pragma unroll
        for (int nt = 0; nt < 4; nt++) {
            const int col = wv * 64 + nt * 16 + lrow;
            const float bb = out_b1[h * HH + col];
            const float w2 = out_W2[h * HH + col];
#pragma unroll
            for (int mt = 0; mt < 2; mt++)
#pragma unroll
                for (int r = 0; r < 4; r++)
                    rs[mt][r] = fmaf(lrelu_(a3[mt][nt][r] + bb), w2, rs[mt][r]);
        }
#pragma unroll
        for (int mt = 0; mt < 2; mt++)
#pragma unroll
            for (int r = 0; r < 4; r++) {
                float v = rs[mt][r];
                v += __shfl_down(v, 8);
                v += __shfl_down(v, 4);
                v += __shfl_down(v, 2);
                v += __shfl_down(v, 1);
                if (lrow == 0) sPart[wv][h][mt * 16 + quad * 4 + r] = v;
            }
    }
    __syncthreads();

    if (t < TILE_V) {
        const int v = v0 + t;
        const int ty = vtypes[v];
        float logit = sPart[0][ty][t] + sPart[1][ty][t] +
                      sPart[2][ty][t] + sPart[3][ty][t] + out_b2[ty];
        const int tr = min(alt_cnt[v], MAX_ALT);
        logit *= conf[tr];
        const float ml = max_logit[0];
        out[v] = ml * tanhf(logit / ml);
    }
}

// ---------------------------------------------------------------------------
extern "C" void kernel_launch(void* const* d_in, const int* in_sizes, int n_in,
                              void* d_out, int out_size, void* d_ws, size_t ws_size,
                              hipStream_t stream) {
    const float* reads    = (const float*)d_in[0];
    const float* info     = (const float*)d_in[1];
    const int*   ref_ids  = (const int*)d_in[2];
    const int*   alt_ids  = (const int*)d_in[3];
    const int*   vtypes   = (const int*)d_in[4];
    const float* phi_W0   = (const float*)d_in[5];
    const float* phi_b0   = (const float*)d_in[6];
    const float* phi_W1   = (const float*)d_in[7];
    const float* phi_b1   = (const float*)d_in[8];
    const float* om_W0    = (const float*)d_in[9];
    const float* om_b0    = (const float*)d_in[10];
    const float* rho_W0   = (const float*)d_in[11];
    const float* rho_b0   = (const float*)d_in[12];
    const float* rho_W1   = (const float*)d_in[13];
    const float* rho_b1   = (const float*)d_in[14];
    const float* out_W1   = (const float*)d_in[15];
    const float* out_b1   = (const float*)d_in[16];
    const float* out_W2   = (const float*)d_in[17];
    const float* out_b2   = (const float*)d_in[18];
    const float* conf     = (const float*)d_in[19];
    const float* max_lg   = (const float*)d_in[20];
    float* out = (float*)d_out;

    // ws: ref_sums | alt_sums | ref_cnt | alt_cnt | w1t_phi | w0t | w1rt | whT
    float* ref_sums = (float*)d_ws;
    float* alt_sums = ref_sums + (size_t)V * HH;
    int*   ref_cnt  = (int*)(alt_sums + (size_t)V * HH);
    int*   alt_cnt  = ref_cnt + V;
    unsigned short* w1t_phi = (unsigned short*)(alt_cnt + V);
    unsigned short* w0t     = w1t_phi + (size_t)HH * HH;
    unsigned short* w1rt    = w0t + (size_t)HH * 768;
    unsigned short* whT     = w1rt + (size_t)HH * HH;

    const size_t zero_bytes = (size_t)2 * V * HH * sizeof(float) + (size_t)2 * V * sizeof(int);
    hipMemsetAsync(d_ws, 0, zero_bytes, stream);

    tr_bf16_kernel<<<dim3(8, 8, 1),  256, 0, stream>>>(phi_W1, w1t_phi, 256, 256, 0, 0);
    tr_bf16_kernel<<<dim3(8, 24, 1), 256, 0, stream>>>(rho_W0, w0t, 768, 256, 0, 0);
    tr_bf16_kernel<<<dim3(8, 8, 1),  256, 0, stream>>>(rho_W1, w1rt, 256, 256, 0, 0);
    tr_bf16_kernel<<<dim3(8, 8, 3),  256, 0, stream>>>(out_W1, whT, 256, 256, HH * HH, HH * HH);

    phi_seg_kernel<<<NREADS / TILE_R, 256, 0, stream>>>(
        reads, ref_ids, alt_ids, phi_W0, phi_b0, w1t_phi, phi_b1,
        ref_sums, alt_sums, ref_cnt, alt_cnt);

    rho_mfma_kernel<<<V / TILE_V, 256, 0, stream>>>(
        info, vtypes, om_W0, om_b0, w0t, rho_b0, w1rt, rho_b1,
        whT, out_b1, out_W2, out_b2, conf, max_lg,
        ref_sums, alt_sums, ref_cnt, alt_cnt, out);
}

// Round 4
// 281.639 us; speedup vs baseline: 3.3835x; 1.2165x over previous
//
#include <hip/hip_runtime.h>
#include <cmath>

#define V 8192
#define NREF 262144
#define NALT 131072
#define NREADS (NREF + NALT)
#define FR 11
#define FI 9
#define HH 256
#define MAX_ALT 10

#define TILE_R 64
#define HPITCH 264   // bf16 H tile pitch (shorts): 528B rows, 16B-aligned
#define PTPITCH 72   // bf16 P^T pitch (shorts): 144B rows, 16B-aligned

#define TILE_V 32
#define CPITCH 776   // bf16 concat pitch (shorts): 1552B, 16B-aligned
#define APITCH 264   // bf16 A1/agg pitch

typedef short bf16x8 __attribute__((ext_vector_type(8)));
typedef float f32x4  __attribute__((ext_vector_type(4)));

__device__ __forceinline__ float sigmoidf_(float x) {
    return __builtin_amdgcn_rcpf(1.0f + __expf(-x));
}
__device__ __forceinline__ float lrelu_(float x) {
    return x > 0.0f ? x : 0.01f * x;
}
__device__ __forceinline__ unsigned short f2bf_(float f) {
    unsigned int u = __float_as_uint(f);
    u += 0x7FFFu + ((u >> 16) & 1u);
    return (unsigned short)(u >> 16);
}
__device__ __forceinline__ float bf2f_(unsigned short b) {
    return __uint_as_float(((unsigned int)b) << 16);
}

// ---------------------------------------------------------------------------
// Tiled transpose + f32->bf16: dst[c][r] = bf16(src[r][c]); src is R x C.
// ---------------------------------------------------------------------------
__global__ void tr_bf16_kernel(const float* __restrict__ src,
                               unsigned short* __restrict__ dst,
                               int R, int C, int sBatch, int dBatch) {
    __shared__ unsigned short sT[32][33];
    const int t = threadIdx.x, tx = t & 31, ty = t >> 5;
    src += (size_t)blockIdx.z * sBatch;
    dst += (size_t)blockIdx.z * dBatch;
    const int r0 = blockIdx.y * 32, c0 = blockIdx.x * 32;
#pragma unroll
    for (int k = 0; k < 4; k++)
        sT[ty + k * 8][tx] = f2bf_(src[(size_t)(r0 + ty + k * 8) * C + c0 + tx]);
    __syncthreads();
#pragma unroll
    for (int k = 0; k < 4; k++)
        dst[(size_t)(c0 + ty + k * 8) * R + r0 + tx] = sT[tx][ty + k * 8];
}

// ---------------------------------------------------------------------------
// Kernel A: fused phi MLP + segment sum/count.
// LDS budget 40192 B -> 4 blocks/CU (launch_bounds(256,4) pins VGPR<=128).
// GEMM1 weights read directly from global (L1/L2-hot, coalesced float4).
// No barrier between sigmoid->sPT write and epilogue read: wave-local cols.
// ---------------------------------------------------------------------------
__global__ __launch_bounds__(256, 4) void phi_seg_kernel(
    const float* __restrict__ reads,
    const int* __restrict__ ref_ids, const int* __restrict__ alt_ids,
    const float* __restrict__ W0, const float* __restrict__ b0,
    const unsigned short* __restrict__ w1t, const float* __restrict__ b1,
    float* __restrict__ ref_sums, float* __restrict__ alt_sums,
    int* __restrict__ ref_cnt, int* __restrict__ alt_cnt)
{
    // union: bf16 H [64][HPITCH] (33792B) | bf16 P^T [256][PTPITCH] (36864B)
    __shared__ __align__(16) unsigned char uSmem[256 * PTPITCH * 2];
    __shared__ __align__(16) float sReads[TILE_R][12];
    __shared__ int sSeg[TILE_R];

    unsigned short* sH  = (unsigned short*)uSmem;
    unsigned short* sPT = (unsigned short*)uSmem;

    const int t  = threadIdx.x;
    const int r0 = blockIdx.x * TILE_R;
    const bool is_ref = (r0 < NREF);
    const int* seg_ids = is_ref ? ref_ids : alt_ids;
    const int sbase    = is_ref ? r0 : (r0 - NREF);
    float* sums = is_ref ? ref_sums : alt_sums;
    int*   cnts = is_ref ? ref_cnt  : alt_cnt;

    for (int idx = t; idx < TILE_R * FR; idx += 256) {
        int r = idx / FR, k = idx - r * FR;
        sReads[r][k] = reads[(size_t)(r0 + r) * FR + k];
    }
    if (t < TILE_R) sSeg[t] = seg_ids[sbase + t];

    // ---- GEMM1 weights: direct global float4 (coalesced, L2-hot) ----
    const int c4 = (t & 63) * 4;
    const int rb = (t >> 6) * 16;
    float4 wr[FR];
#pragma unroll
    for (int k = 0; k < FR; k++) wr[k] = *(const float4*)(W0 + k * HH + c4);
    const float4 bias0 = *(const float4*)(b0 + c4);
    __syncthreads();

    // ---- GEMM1: 4 cols x 16 rows per thread ----
#pragma unroll
    for (int rr = 0; rr < 16; rr++) {
        const int r = rb + rr;
        float4 f0 = *(const float4*)&sReads[r][0];
        float4 f1 = *(const float4*)&sReads[r][4];
        float4 f2 = *(const float4*)&sReads[r][8];
        float fr_[FR] = {f0.x, f0.y, f0.z, f0.w, f1.x, f1.y, f1.z, f1.w,
                         f2.x, f2.y, f2.z};
        float4 a = bias0;
#pragma unroll
        for (int k = 0; k < FR; k++) {
            a.x = fmaf(fr_[k], wr[k].x, a.x);
            a.y = fmaf(fr_[k], wr[k].y, a.y);
            a.z = fmaf(fr_[k], wr[k].z, a.z);
            a.w = fmaf(fr_[k], wr[k].w, a.w);
        }
        unsigned int p01 = (unsigned int)f2bf_(lrelu_(a.x)) |
                           ((unsigned int)f2bf_(lrelu_(a.y)) << 16);
        unsigned int p23 = (unsigned int)f2bf_(lrelu_(a.z)) |
                           ((unsigned int)f2bf_(lrelu_(a.w)) << 16);
        uint2 pk = {p01, p23};
        *(uint2*)&sH[r * HPITCH + c4] = pk;
    }
    __syncthreads();

    // ---- GEMM2 via MFMA: 64x64 per wave ----
    const int wv   = t >> 6;
    const int lane = t & 63;
    const int lrow = lane & 15;
    const int quad = lane >> 4;

    f32x4 acc[4][4];
#pragma unroll
    for (int mt = 0; mt < 4; mt++)
#pragma unroll
        for (int nt = 0; nt < 4; nt++)
            acc[mt][nt] = (f32x4){0.f, 0.f, 0.f, 0.f};

#pragma unroll
    for (int kk = 0; kk < 8; kk++) {
        bf16x8 am[4], bn[4];
#pragma unroll
        for (int mt = 0; mt < 4; mt++)
            am[mt] = *(const bf16x8*)(sH + (mt * 16 + lrow) * HPITCH + kk * 32 + quad * 8);
#pragma unroll
        for (int nt = 0; nt < 4; nt++)
            bn[nt] = *(const bf16x8*)(w1t + (size_t)(wv * 64 + nt * 16 + lrow) * HH + kk * 32 + quad * 8);
#pragma unroll
        for (int mt = 0; mt < 4; mt++)
#pragma unroll
            for (int nt = 0; nt < 4; nt++)
                acc[mt][nt] = __builtin_amdgcn_mfma_f32_16x16x32_bf16(
                    am[mt], bn[nt], acc[mt][nt], 0, 0, 0);
    }
    __syncthreads();   // all waves done reading sH; union becomes sPT

    // ---- sigmoid -> P^T (bf16); cols wv*64..wv*64+63 are wave-local ----
#pragma unroll
    for (int nt = 0; nt < 4; nt++) {
        const int col = wv * 64 + nt * 16 + lrow;
        const float bb = b1[col];
#pragma unroll
        for (int mt = 0; mt < 4; mt++) {
            unsigned int p01 =
                (unsigned int)f2bf_(sigmoidf_(acc[mt][nt][0] + bb)) |
                ((unsigned int)f2bf_(sigmoidf_(acc[mt][nt][1] + bb)) << 16);
            unsigned int p23 =
                (unsigned int)f2bf_(sigmoidf_(acc[mt][nt][2] + bb)) |
                ((unsigned int)f2bf_(sigmoidf_(acc[mt][nt][3] + bb)) << 16);
            uint2 pk = {p01, p23};
            *(uint2*)&sPT[col * PTPITCH + mt * 16 + quad * 4] = pk;
        }
    }
    // NO barrier: thread t reads col t, written by its own wave (lgkmcnt
    // dependency wait is compiler-inserted; DS pipe is in-order per wave).

    // ---- per-column run-compressed segment atomics (regs only) ----
    bf16x8 p8[8];
#pragma unroll
    for (int j = 0; j < 8; j++)
        p8[j] = *(const bf16x8*)&sPT[t * PTPITCH + j * 8];

    int cur = sSeg[0];
    float run = 0.f;
    int runlen = 0;
#pragma unroll
    for (int r = 0; r < TILE_R; r++) {
        const int s = sSeg[r];
        if (s != cur) {
            atomicAdd(&sums[(size_t)cur * HH + t], run);
            if (t == 0) atomicAdd(&cnts[cur], runlen);
            run = 0.f; runlen = 0; cur = s;
        }
        run += bf2f_((unsigned short)p8[r >> 3][r & 7]);
        runlen++;
    }
    atomicAdd(&sums[(size_t)cur * HH + t], run);
    if (t == 0) atomicAdd(&cnts[cur], runlen);
}

// ---------------------------------------------------------------------------
// Kernel B: fused MFMA chain (unchanged this round).
// ---------------------------------------------------------------------------
__global__ __launch_bounds__(256) void rho_mfma_kernel(
    const float* __restrict__ info, const int* __restrict__ vtypes,
    const float* __restrict__ om_W0, const float* __restrict__ om_b0,
    const unsigned short* __restrict__ w0t, const float* __restrict__ rho_b0,
    const unsigned short* __restrict__ w1rt, const float* __restrict__ rho_b1,
    const unsigned short* __restrict__ whT, const float* __restrict__ out_b1,
    const float* __restrict__ out_W2, const float* __restrict__ out_b2,
    const float* __restrict__ conf, const float* __restrict__ max_logit,
    const float* __restrict__ ref_sums, const float* __restrict__ alt_sums,
    const int* __restrict__ ref_cnt, const int* __restrict__ alt_cnt,
    float* __restrict__ out)
{
    __shared__ __align__(16) unsigned short sC[TILE_V * CPITCH];
    __shared__ __align__(16) float sInfo[TILE_V][12];
    __shared__ float sRinvR[TILE_V], sRinvA[TILE_V];
    __shared__ float sPart[4][3][TILE_V];

    unsigned short* sA1  = sC;
    unsigned short* sAgg = sC + TILE_V * APITCH;

    const int t  = threadIdx.x;
    const int v0 = blockIdx.x * TILE_V;

    for (int idx = t; idx < TILE_V * FI; idx += 256) {
        int i = idx / FI, k = idx - i * FI;
        sInfo[i][k] = info[(size_t)(v0 + i) * FI + k];
    }
    if (t < TILE_V) {
        sRinvR[t] = __builtin_amdgcn_rcpf(fmaxf((float)ref_cnt[v0 + t], 1.0f));
        sRinvA[t] = __builtin_amdgcn_rcpf(fmaxf((float)alt_cnt[v0 + t], 1.0f));
    }
    float om0r[FI];
#pragma unroll
    for (int k = 0; k < FI; k++) om0r[k] = om_W0[k * HH + t];
    const float omb = om_b0[t];
    __syncthreads();

    for (int i = 0; i < TILE_V; i++) {
        sC[i * CPITCH + t]          = f2bf_(ref_sums[(size_t)(v0 + i) * HH + t] * sRinvR[i]);
        sC[i * CPITCH + HH + t]     = f2bf_(alt_sums[(size_t)(v0 + i) * HH + t] * sRinvA[i]);
        float a = omb;
#pragma unroll
        for (int k = 0; k < FI; k++) a = fmaf(sInfo[i][k], om0r[k], a);
        sC[i * CPITCH + 2 * HH + t] = f2bf_(sigmoidf_(a));
    }
    __syncthreads();

    const int wv   = t >> 6;
    const int lane = t & 63;
    const int lrow = lane & 15;
    const int quad = lane >> 4;

    f32x4 acc[2][4];
#pragma unroll
    for (int mt = 0; mt < 2; mt++)
#pragma unroll
        for (int nt = 0; nt < 4; nt++) acc[mt][nt] = (f32x4){0.f, 0.f, 0.f, 0.f};

    for (int kk = 0; kk < 24; kk++) {
        bf16x8 am[2], bn[4];
#pragma unroll
        for (int mt = 0; mt < 2; mt++)
            am[mt] = *(const bf16x8*)&sC[(mt * 16 + lrow) * CPITCH + kk * 32 + quad * 8];
#pragma unroll
        for (int nt = 0; nt < 4; nt++)
            bn[nt] = *(const bf16x8*)&w0t[(size_t)(wv * 64 + nt * 16 + lrow) * 768 + kk * 32 + quad * 8];
#pragma unroll
        for (int mt = 0; mt < 2; mt++)
#pragma unroll
            for (int nt = 0; nt < 4; nt++)
                acc[mt][nt] = __builtin_amdgcn_mfma_f32_16x16x32_bf16(
                    am[mt], bn[nt], acc[mt][nt], 0, 0, 0);
    }
    __syncthreads();

#pragma unroll
    for (int nt = 0; nt < 4; nt++) {
        const int col = wv * 64 + nt * 16 + lrow;
        const float bb = rho_b0[col];
#pragma unroll
        for (int mt = 0; mt < 2; mt++)
#pragma unroll
            for (int r = 0; r < 4; r++)
                sA1[(mt * 16 + quad * 4 + r) * APITCH + col] = f2bf_(lrelu_(acc[mt][nt][r] + bb));
    }
    __syncthreads();

#pragma unroll
    for (int mt = 0; mt < 2; mt++)
#pragma unroll
        for (int nt = 0; nt < 4; nt++) acc[mt][nt] = (f32x4){0.f, 0.f, 0.f, 0.f};

#pragma unroll
    for (int kk = 0; kk < 8; kk++) {
        bf16x8 am[2], bn[4];
#pragma unroll
        for (int mt = 0; mt < 2; mt++)
            am[mt] = *(const bf16x8*)&sA1[(mt * 16 + lrow) * APITCH + kk * 32 + quad * 8];
#pragma unroll
        for (int nt = 0; nt < 4; nt++)
            bn[nt] = *(const bf16x8*)&w1rt[(size_t)(wv * 64 + nt * 16 + lrow) * HH + kk * 32 + quad * 8];
#pragma unroll
        for (int mt = 0; mt < 2; mt++)
#pragma unroll
            for (int nt = 0; nt < 4; nt++)
                acc[mt][nt] = __builtin_amdgcn_mfma_f32_16x16x32_bf16(
                    am[mt], bn[nt], acc[mt][nt], 0, 0, 0);
    }
#pragma unroll
    for (int nt = 0; nt < 4; nt++) {
        const int col = wv * 64 + nt * 16 + lrow;
        const float bb = rho_b1[col];
#pragma unroll
        for (int mt = 0; mt < 2; mt++)
#pragma unroll
            for (int r = 0; r < 4; r++)
                sAgg[(mt * 16 + quad * 4 + r) * APITCH + col] = f2bf_(acc[mt][nt][r] + bb);
    }
    __syncthreads();

    bf16x8 aF[8][2];
#pragma unroll
    for (int kk = 0; kk < 8; kk++)
#pragma unroll
        for (int mt = 0; mt < 2; mt++)
            aF[kk][mt] = *(const bf16x8*)&sAgg[(mt * 16 + lrow) * APITCH + kk * 32 + quad * 8];

    for (int h = 0; h < 3; h++) {
        f32x4 a3[2][4];
#pragma unroll
        for (int mt = 0; mt < 2; mt++)
#pragma unroll
            for (int nt = 0; nt < 4; nt++) a3[mt][nt] = (f32x4){0.f, 0.f, 0.f, 0.f};

#pragma unroll
        for (int kk = 0; kk < 8; kk++) {
            bf16x8 bn[4];
#pragma unroll
            for (int nt = 0; nt < 4; nt++)
                bn[nt] = *(const bf16x8*)&whT[((size_t)h * HH + wv * 64 + nt * 16 + lrow) * HH + kk * 32 + quad * 8];
#pragma unroll
            for (int mt = 0; mt < 2; mt++)
#pragma unroll
                for (int nt = 0; nt < 4; nt++)
                    a3[mt][nt] = __builtin_amdgcn_mfma_f32_16x16x32_bf16(
                        aF[kk][mt], bn[nt], a3[mt][nt], 0, 0, 0);
        }

        float rs[2][4] = {{0.f, 0.f, 0.f, 0.f}, {0.f, 0.f, 0.f, 0.f}};
#pragma unroll
        for (int nt = 0; nt < 4; nt++) {
            const int col = wv * 64 + nt * 16 + lrow;
            const float bb = out_b1[h * HH + col];
            const float w2 = out_W2[h * HH + col];
#pragma unroll
            for (int mt = 0; mt < 2; mt++)
#pragma unroll
                for (int r = 0; r < 4; r++)
                    rs[mt][r] = fmaf(lrelu_(a3[mt][nt][r] + bb), w2, rs[mt][r]);
        }
#pragma unroll
        for (int mt = 0; mt < 2; mt++)
#pragma unroll
            for (int r = 0; r < 4; r++) {
                float v = rs[mt][r];
                v += __shfl_down(v, 8);
                v += __shfl_down(v, 4);
                v += __shfl_down(v, 2);
                v += __shfl_down(v, 1);
                if (lrow == 0) sPart[wv][h][mt * 16 + quad * 4 + r] = v;
            }
    }
    __syncthreads();

    if (t < TILE_V) {
        const int v = v0 + t;
        const int ty = vtypes[v];
        float logit = sPart[0][ty][t] + sPart[1][ty][t] +
                      sPart[2][ty][t] + sPart[3][ty][t] + out_b2[ty];
        const int tr = min(alt_cnt[v], MAX_ALT);
        logit *= conf[tr];
        const float ml = max_logit[0];
        out[v] = ml * tanhf(logit / ml);
    }
}

// ---------------------------------------------------------------------------
extern "C" void kernel_launch(void* const* d_in, const int* in_sizes, int n_in,
                              void* d_out, int out_size, void* d_ws, size_t ws_size,
                              hipStream_t stream) {
    const float* reads    = (const float*)d_in[0];
    const float* info     = (const float*)d_in[1];
    const int*   ref_ids  = (const int*)d_in[2];
    const int*   alt_ids  = (const int*)d_in[3];
    const int*   vtypes   = (const int*)d_in[4];
    const float* phi_W0   = (const float*)d_in[5];
    const float* phi_b0   = (const float*)d_in[6];
    const float* phi_W1   = (const float*)d_in[7];
    const float* phi_b1   = (const float*)d_in[8];
    const float* om_W0    = (const float*)d_in[9];
    const float* om_b0    = (const float*)d_in[10];
    const float* rho_W0   = (const float*)d_in[11];
    const float* rho_b0   = (const float*)d_in[12];
    const float* rho_W1   = (const float*)d_in[13];
    const float* rho_b1   = (const float*)d_in[14];
    const float* out_W1   = (const float*)d_in[15];
    const float* out_b1   = (const float*)d_in[16];
    const float* out_W2   = (const float*)d_in[17];
    const float* out_b2   = (const float*)d_in[18];
    const float* conf     = (const float*)d_in[19];
    const float* max_lg   = (const float*)d_in[20];
    float* out = (float*)d_out;

    float* ref_sums = (float*)d_ws;
    float* alt_sums = ref_sums + (size_t)V * HH;
    int*   ref_cnt  = (int*)(alt_sums + (size_t)V * HH);
    int*   alt_cnt  = ref_cnt + V;
    unsigned short* w1t_phi = (unsigned short*)(alt_cnt + V);
    unsigned short* w0t     = w1t_phi + (size_t)HH * HH;
    unsigned short* w1rt    = w0t + (size_t)HH * 768;
    unsigned short* whT     = w1rt + (size_t)HH * HH;

    const size_t zero_bytes = (size_t)2 * V * HH * sizeof(float) + (size_t)2 * V * sizeof(int);
    hipMemsetAsync(d_ws, 0, zero_bytes, stream);

    tr_bf16_kernel<<<dim3(8, 8, 1),  256, 0, stream>>>(phi_W1, w1t_phi, 256, 256, 0, 0);
    tr_bf16_kernel<<<dim3(8, 24, 1), 256, 0, stream>>>(rho_W0, w0t, 768, 256, 0, 0);
    tr_bf16_kernel<<<dim3(8, 8, 1),  256, 0, stream>>>(rho_W1, w1rt, 256, 256, 0, 0);
    tr_bf16_kernel<<<dim3(8, 8, 3),  256, 0, stream>>>(out_W1, whT, 256, 256, HH * HH, HH * HH);

    phi_seg_kernel<<<NREADS / TILE_R, 256, 0, stream>>>(
        reads, ref_ids, alt_ids, phi_W0, phi_b0, w1t_phi, phi_b1,
        ref_sums, alt_sums, ref_cnt, alt_cnt);

    rho_mfma_kernel<<<V / TILE_V, 256, 0, stream>>>(
        info, vtypes, om_W0, om_b0, w0t, rho_b0, w1rt, rho_b1,
        whT, out_b1, out_W2, out_b2, conf, max_lg,
        ref_sums, alt_sums, ref_cnt, alt_cnt, out);
}